// Round 2
// baseline (387.213 us; speedup 1.0000x reference)
//
#include <hip/hip_runtime.h>

// SelfAttention: x(4,2048,1024) fp32; Linear y = x @ W^T + b for Q,K,V;
// S = QK^T/32; P = softmax(S); O = P V; out = O @ Wo^T + bo.
// R4 == R3 resubmit (container infra failure, kernel never executed).
// 256x256 8-phase counted-vmcnt GEMM engine (guide §5 template, T2+T3+T4+T5):
//   - BM=BN=256, BK=64, 512 thr = 8 waves (2M x 4N), each wave owns 128x64 out.
//   - LDS 128 KiB: 2 dbuf x {A,B} x 2 halves x [128][64] bf16.
//   - Staging: global_load_lds dwordx4, one half-tile (2 loads/thread) per phase;
//     vmcnt(4) only at phases 4 and 8 (counted, never 0 in main loop).
//   - chunk ^= (row&7) XOR swizzle (pre-swizzled global src + swizzled ds_read;
//     measured SQ_LDS_BANK_CONFLICT == 0 with this involution in R1/R2).
//   - raw s_barrier + asm lgkmcnt(0), s_setprio(1) around each 16-MFMA cluster.
// Also: fused QKV projection (one [8192,3072,1024] GEMM; weights contiguous
// in ws), bias concat kernel, lda/ldb for column-sliced QKV reads.
//
// Workspace layout (136 MB, aliased by lifetime):
//   [0,16)MB    x_bf16        -> later VT (transpose runs after QKV gemm)
//   [16,22)MB   wq|wk|wv bf16 (contiguous -> fused [3072][1024] weight)
//   [22,24)MB   wo bf16
//   [24,72)MB   QKV bf16 [8192][3072] -> after QK^T: P=[24,56), O=[56,72)
//   [72,136)MB  S fp32 [4][2048][2048]; bqkv (12KB) lives at 72MB before S

typedef __bf16 bf16x8 __attribute__((ext_vector_type(8)));
typedef float f32x4 __attribute__((ext_vector_type(4)));

__device__ __forceinline__ unsigned short f32_to_bf16(float f) {
  unsigned int u = __float_as_uint(f);
  u += 0x7fffu + ((u >> 16) & 1u);   // round-to-nearest-even
  return (unsigned short)(u >> 16);
}

__device__ __forceinline__ void load_lds16(const void* g, void* l) {
  __builtin_amdgcn_global_load_lds(
      (const __attribute__((address_space(1))) void*)g,
      (__attribute__((address_space(3))) void*)l, 16, 0, 0);
}

// ---------------------------------------------------------------- cast kernel
__global__ __launch_bounds__(256) void cast_f32_bf16(
    const float4* __restrict__ in, ushort4* __restrict__ out, int n4) {
  int i = blockIdx.x * 256 + threadIdx.x;
  if (i < n4) {
    float4 f = in[i];
    ushort4 u;
    u.x = f32_to_bf16(f.x);
    u.y = f32_to_bf16(f.y);
    u.z = f32_to_bf16(f.z);
    u.w = f32_to_bf16(f.w);
    out[i] = u;
  }
}

// ------------------------------------------------------------ bias concat
__global__ __launch_bounds__(256) void concat3(
    const float* __restrict__ a, const float* __restrict__ b,
    const float* __restrict__ c, float* __restrict__ o) {
  int i = blockIdx.x * 256 + threadIdx.x;  // grid 12 -> i < 3072
  if (i < 1024)
    o[i] = a[i];
  else if (i < 2048)
    o[i] = b[i - 1024];
  else if (i < 3072)
    o[i] = c[i - 2048];
}

// --------------------------------------------- gemm (B^T form), 256^2 8-phase
// C[b][M][N] = alpha * A[b][M][K] * B[b][N][K]^T + bias[N]
// A row stride lda, B row stride ldb (for column-sliced QKV views).
// Requires M%256==0, N%256==0, K%128==0.
__global__ __launch_bounds__(512, 2) void gemm_bt256(
    const unsigned short* __restrict__ A, const unsigned short* __restrict__ B,
    void* __restrict__ C, const float* __restrict__ bias,
    int M, int N, int K, float alpha, int out_bf16, int lda, int ldb,
    long long sA, long long sB, long long sC) {
  __shared__ unsigned short As[2][2][128][64];  // [dbuf][half][row][k] 64KB
  __shared__ unsigned short Bs[2][2][128][64];  // 64KB

  const int bz = blockIdx.z;
  A += (long long)bz * sA;
  B += (long long)bz * sB;

  const int bm = blockIdx.y, bn = blockIdx.x;
  const int tid = threadIdx.x;
  const int lane = tid & 63, wave = tid >> 6;
  const int wr = wave >> 2;                 // M half of tile (0..1)
  const int wc = wave & 3;                  // N quarter of tile (0..3)
  const int l16 = lane & 15, quad = lane >> 4;
  const int wbh = wc >> 1;                  // which B half this wave reads
  const int wbr = (wc & 1) * 64 + l16;      // B row base within that half
  // swizzled 16B-chunk element offsets for the two K-slices (row&7 == l16&7)
  const int pc0 = (quad ^ (l16 & 7)) * 8;
  const int pc1 = ((4 + quad) ^ (l16 & 7)) * 8;

  // staging map: thread t covers LDS rows srow (j=0) and srow+64 (j=1),
  // physical chunk t&7 -> fetch logical (swizzled) chunk lch from global.
  const int srow = tid >> 3;
  const int lch = (tid & 7) ^ (srow & 7);
  const unsigned short* gA0 = A + (long long)(bm * 256 + srow) * lda + lch * 8;
  const unsigned short* gB0 = B + (long long)(bn * 256 + srow) * ldb + lch * 8;

  f32x4 acc[8][4] = {};
  bf16x8 af[2][2];  // current mi-pair fragments (loaded per phase)
  bf16x8 bf[4][2];  // whole-tile B fragments (loaded at ph1/ph5)

  const int NT = K >> 6;  // 64-wide K tiles; NT even (K % 128 == 0)

#define STAGE(GP, LB, BUF, H, KT, LD)                                       \
  do {                                                                      \
    const unsigned short* _s =                                              \
        (GP) + (long long)(H) * 128 * (LD) + (KT) * 64;                     \
    char* _d = (char*)(LB) + ((BUF) * 2 + (H)) * 16384 + wave * 1024;       \
    load_lds16(_s, _d);                                                     \
    load_lds16(_s + (long long)64 * (LD), _d + 8192);                       \
  } while (0)

#define DSA2(BUF, MIP)                                                      \
  do {                                                                      \
    _Pragma("unroll") for (int m2 = 0; m2 < 2; ++m2) {                      \
      const unsigned short* _r =                                            \
          &As[BUF][wr][(MIP) * 32 + m2 * 16 + l16][0];                      \
      af[m2][0] = *(const bf16x8*)(_r + pc0);                               \
      af[m2][1] = *(const bf16x8*)(_r + pc1);                               \
    }                                                                       \
  } while (0)

#define DSB8(BUF)                                                           \
  do {                                                                      \
    _Pragma("unroll") for (int ni = 0; ni < 4; ++ni) {                      \
      const unsigned short* _r = &Bs[BUF][wbh][wbr + ni * 16][0];           \
      bf[ni][0] = *(const bf16x8*)(_r + pc0);                               \
      bf[ni][1] = *(const bf16x8*)(_r + pc1);                               \
    }                                                                       \
  } while (0)

#define MMP(MIP)                                                            \
  do {                                                                      \
    _Pragma("unroll") for (int m2 = 0; m2 < 2; ++m2)                        \
        _Pragma("unroll") for (int ni = 0; ni < 4; ++ni) {                  \
      f32x4* _a = &acc[(MIP) * 2 + m2][ni];                                 \
      *_a = __builtin_amdgcn_mfma_f32_16x16x32_bf16(af[m2][0], bf[ni][0],   \
                                                    *_a, 0, 0, 0);          \
      *_a = __builtin_amdgcn_mfma_f32_16x16x32_bf16(af[m2][1], bf[ni][1],   \
                                                    *_a, 0, 0, 0);          \
    }                                                                       \
  } while (0)

#define BAR() __builtin_amdgcn_s_barrier()
#define WLG() asm volatile("s_waitcnt lgkmcnt(0)" ::: "memory")
#define WVM4() asm volatile("s_waitcnt vmcnt(4)" ::: "memory")
#define P1() __builtin_amdgcn_s_setprio(1)
#define P0() __builtin_amdgcn_s_setprio(0)

  // prologue: tile0 (A0,A1,B0,B1 -> buf0), tile1 (B0,B1 -> buf1); the 4
  // newest loads (tile1 B) may stay in flight across the wait.
  STAGE(gA0, As, 0, 0, 0, lda);
  STAGE(gA0, As, 0, 1, 0, lda);
  STAGE(gB0, Bs, 0, 0, 0, ldb);
  STAGE(gB0, Bs, 0, 1, 0, ldb);
  STAGE(gB0, Bs, 1, 0, 1, ldb);
  STAGE(gB0, Bs, 1, 1, 1, ldb);
  WVM4();
  BAR();

  // Per iteration (tiles t=2i in buf0, t+1 in buf1), stage order:
  //  ph1:A0(t+1)->buf1  ph2:A1(t+1)->buf1  ph3:B0(t+2)->buf0  ph4:B1(t+2)->buf0
  //  ph5:A0(t+2)->buf0  ph6:A1(t+2)->buf0  ph7:B0(t+3)->buf1  ph8:B1(t+3)->buf1
  // Every staged half is written >=1 barrier after its last ds_read; vmcnt(4)
  // at ph4 lands everything through ph2 (tile t+1 complete before ph5 reads);
  // at ph8 lands through ph6 (tile t+2 complete before next ph1 reads).
  for (int it = 0; it < (NT >> 1); ++it) {
    const int t = 2 * it;
    const int tn1 = t + 1;
    const int tn2 = (t + 2 < NT) ? t + 2 : NT - 1;  // clamped restage of the
    const int tn3 = (t + 3 < NT) ? t + 3 : NT - 1;  // last tile is harmless
    // ph1
    DSB8(0);
    DSA2(0, 0);
    STAGE(gA0, As, 1, 0, tn1, lda);
    BAR();
    WLG();
    P1();
    MMP(0);
    P0();
    BAR();
    // ph2
    DSA2(0, 1);
    STAGE(gA0, As, 1, 1, tn1, lda);
    BAR();
    WLG();
    P1();
    MMP(1);
    P0();
    BAR();
    // ph3
    DSA2(0, 2);
    STAGE(gB0, Bs, 0, 0, tn2, ldb);
    BAR();
    WLG();
    P1();
    MMP(2);
    P0();
    BAR();
    // ph4
    DSA2(0, 3);
    STAGE(gB0, Bs, 0, 1, tn2, ldb);
    BAR();
    WLG();
    P1();
    MMP(3);
    P0();
    WVM4();
    BAR();
    // ph5
    DSB8(1);
    DSA2(1, 0);
    STAGE(gA0, As, 0, 0, tn2, lda);
    BAR();
    WLG();
    P1();
    MMP(0);
    P0();
    BAR();
    // ph6
    DSA2(1, 1);
    STAGE(gA0, As, 0, 1, tn2, lda);
    BAR();
    WLG();
    P1();
    MMP(1);
    P0();
    BAR();
    // ph7
    DSA2(1, 2);
    STAGE(gB0, Bs, 1, 0, tn3, ldb);
    BAR();
    WLG();
    P1();
    MMP(2);
    P0();
    BAR();
    // ph8
    DSA2(1, 3);
    STAGE(gB0, Bs, 1, 1, tn3, ldb);
    BAR();
    WLG();
    P1();
    MMP(3);
    P0();
    WVM4();
    BAR();
  }
  // drain DMA before LDS deallocation / endpgm
  asm volatile("s_waitcnt vmcnt(0)" ::: "memory");

  // epilogue: D row = quad*4+r, col = l16 within each 16x16 tile
  const long long orow0 = (long long)bm * 256 + wr * 128 + quad * 4;
  const int ocol0 = bn * 256 + wc * 64 + l16;
  if (out_bf16) {
    unsigned short* Cp = (unsigned short*)C + (long long)bz * sC;
#pragma unroll
    for (int mi = 0; mi < 8; ++mi)
#pragma unroll
      for (int ni = 0; ni < 4; ++ni) {
        const int col = ocol0 + ni * 16;
        const float bv = bias ? bias[col] : 0.f;
#pragma unroll
        for (int r = 0; r < 4; ++r) {
          const float o = acc[mi][ni][r] * alpha + bv;
          Cp[(orow0 + mi * 16 + r) * N + col] = f32_to_bf16(o);
        }
      }
  } else {
    float* Cp = (float*)C + (long long)bz * sC;
#pragma unroll
    for (int mi = 0; mi < 8; ++mi)
#pragma unroll
      for (int ni = 0; ni < 4; ++ni) {
        const int col = ocol0 + ni * 16;
        const float bv = bias ? bias[col] : 0.f;
#pragma unroll
        for (int r = 0; r < 4; ++r) {
          const float o = acc[mi][ni][r] * alpha + bv;
          Cp[(orow0 + mi * 16 + r) * N + col] = o;
        }
      }
  }
#undef STAGE
#undef DSA2
#undef DSB8
#undef MMP
#undef BAR
#undef WLG
#undef WVM4
#undef P1
#undef P0
}

// ------------------------------------------------------- V transpose (bf16)
// V view: [4*2048][ldv] at column offset already folded into pointer.
// VT: [4][1024][2048]
__global__ __launch_bounds__(256) void transpose_v(
    const unsigned short* __restrict__ V, unsigned short* __restrict__ VT,
    int ldv) {
  __shared__ unsigned short tile[64][65];
  const int d0 = blockIdx.x * 64, s0 = blockIdx.y * 64, b = blockIdx.z;
  const int t = threadIdx.x;
  const unsigned short* src = V + ((long long)b * 2048 + s0) * ldv + d0;
#pragma unroll
  for (int i = 0; i < 16; i++) {
    int lin = t + i * 256;
    int r = lin >> 6, c = lin & 63;  // r: s-offset, c: d-offset
    tile[r][c] = src[(long long)r * ldv + c];
  }
  __syncthreads();
  unsigned short* dst = VT + ((long long)b * 1024 + d0) * 2048 + s0;
#pragma unroll
  for (int i = 0; i < 16; i++) {
    int lin = t + i * 256;
    int r = lin >> 6, c = lin & 63;  // r: d-offset, c: s-offset
    dst[(long long)r * 2048 + c] = tile[c][r];
  }
}

// ------------------------------------------------------------- row softmax
// S: [8192][2048] fp32 -> P: [8192][2048] bf16. One block per row.
__global__ __launch_bounds__(256) void softmax_rows(
    const float* __restrict__ S, unsigned short* __restrict__ P) {
  const long long row = blockIdx.x;
  const float* s = S + row * 2048;
  const int t = threadIdx.x;
  float v[8];
  float mx = -3.4e38f;
#pragma unroll
  for (int i = 0; i < 8; i++) {
    v[i] = s[t + i * 256];
    mx = fmaxf(mx, v[i]);
  }
#pragma unroll
  for (int o = 32; o >= 1; o >>= 1) mx = fmaxf(mx, __shfl_xor(mx, o));
  __shared__ float red[4], red2[4];
  if ((t & 63) == 0) red[t >> 6] = mx;
  __syncthreads();
  mx = fmaxf(fmaxf(red[0], red[1]), fmaxf(red[2], red[3]));
  float sum = 0.f;
#pragma unroll
  for (int i = 0; i < 8; i++) {
    v[i] = __expf(v[i] - mx);
    sum += v[i];
  }
#pragma unroll
  for (int o = 32; o >= 1; o >>= 1) sum += __shfl_xor(sum, o);
  if ((t & 63) == 0) red2[t >> 6] = sum;
  __syncthreads();
  sum = red2[0] + red2[1] + red2[2] + red2[3];
  const float inv = 1.0f / sum;
  unsigned short* p = P + row * 2048;
#pragma unroll
  for (int i = 0; i < 8; i++) p[t + i * 256] = f32_to_bf16(v[i] * inv);
}

// ----------------------------------------------------------------- launcher
extern "C" void kernel_launch(void* const* d_in, const int* in_sizes, int n_in,
                              void* d_out, int out_size, void* d_ws,
                              size_t ws_size, hipStream_t stream) {
  const float* x = (const float*)d_in[0];
  const float* wq = (const float*)d_in[1];
  const float* bq = (const float*)d_in[2];
  const float* wk = (const float*)d_in[3];
  const float* bk = (const float*)d_in[4];
  const float* wv = (const float*)d_in[5];
  const float* bv = (const float*)d_in[6];
  const float* wo = (const float*)d_in[7];
  const float* bo = (const float*)d_in[8];
  float* out = (float*)d_out;
  char* ws = (char*)d_ws;
  const size_t MB = 1ull << 20;

  unsigned short* xb   = (unsigned short*)(ws + 0);        // 16MB, later VT
  unsigned short* wqkv = (unsigned short*)(ws + 16 * MB);  // 6MB [3072][1024]
  unsigned short* wkb  = (unsigned short*)(ws + 18 * MB);
  unsigned short* wvb  = (unsigned short*)(ws + 20 * MB);
  unsigned short* wob  = (unsigned short*)(ws + 22 * MB);  // 2MB
  unsigned short* QKV  = (unsigned short*)(ws + 24 * MB);  // 48MB [8192][3072]
  float*          S    = (float*)(ws + 72 * MB);           // 64MB
  float*          bqkv = (float*)(ws + 72 * MB);           // 12KB, dies at S
  unsigned short* VT   = xb;                               // 16MB over x_bf16
  unsigned short* P    = QKV;                              // 32MB over QKV
  unsigned short* O    = (unsigned short*)(ws + 56 * MB);  // 16MB over QKV tail

  // 1) casts to bf16 (wq|wk|wv land contiguously -> fused weight)
  cast_f32_bf16<<<dim3(8192), dim3(256), 0, stream>>>((const float4*)x,
                                                      (ushort4*)xb, 2097152);
  cast_f32_bf16<<<dim3(1024), dim3(256), 0, stream>>>((const float4*)wq,
                                                      (ushort4*)wqkv, 262144);
  cast_f32_bf16<<<dim3(1024), dim3(256), 0, stream>>>((const float4*)wk,
                                                      (ushort4*)wkb, 262144);
  cast_f32_bf16<<<dim3(1024), dim3(256), 0, stream>>>((const float4*)wv,
                                                      (ushort4*)wvb, 262144);
  cast_f32_bf16<<<dim3(1024), dim3(256), 0, stream>>>((const float4*)wo,
                                                      (ushort4*)wob, 262144);
  concat3<<<dim3(12), dim3(256), 0, stream>>>(bq, bk, bv, bqkv);

  // 2) fused QKV projection: [8192,3072] = x_bf16 @ [wq;wk;wv]^T + bqkv
  gemm_bt256<<<dim3(12, 32, 1), dim3(512), 0, stream>>>(
      xb, wqkv, QKV, bqkv, 8192, 3072, 1024, 1.f, 1, 1024, 1024, 0, 0, 0);

  // 3) V (cols [2048,3072) of QKV) -> VT [4][1024][2048]
  transpose_v<<<dim3(16, 32, 4), dim3(256), 0, stream>>>(QKV + 2048, VT, 3072);

  // 4) S = Q K^T / 32, fp32, batched over 4 (Q,K are column slices of QKV)
  gemm_bt256<<<dim3(8, 8, 4), dim3(512), 0, stream>>>(
      QKV, QKV + 1024, S, nullptr, 2048, 2048, 1024, 0.03125f, 0, 3072, 3072,
      2048ll * 3072, 2048ll * 3072, 2048ll * 2048);

  // 5) P = softmax rows of S (bf16), over dead Q/K region
  softmax_rows<<<dim3(8192), dim3(256), 0, stream>>>(S, P);

  // 6) O = P @ V (via VT, B^T form), bf16
  gemm_bt256<<<dim3(4, 8, 4), dim3(512), 0, stream>>>(
      P, VT, O, nullptr, 2048, 1024, 2048, 1.f, 1, 2048, 2048, 2048ll * 2048,
      1024ll * 2048, 2048ll * 1024);

  // 7) out = O @ Wo^T + bo, fp32 to d_out
  gemm_bt256<<<dim3(4, 32, 1), dim3(512), 0, stream>>>(
      O, wob, out, bo, 8192, 1024, 1024, 1.f, 0, 1024, 1024, 0, 0, 0);
}

// Round 3
// 314.563 us; speedup vs baseline: 1.2310x; 1.2310x over previous
//
#include <hip/hip_runtime.h>

// SelfAttention: x(4,2048,1024) fp32; Linear y = x @ W^T + b for Q,K,V;
// S = QK^T/32; P = softmax(S); O = P V; out = O @ Wo^T + bo.
// R5: 128x256 triple-buffered 2-phase-per-K-tile GEMM engine.
//   R4 post-mortem: 256^2 tile gave perfect per-CU gains (+28%) but broke the
//   grid: QKV 384 blocks = 1.5 rounds, PV/out-proj 128 blocks = half machine.
//   BM=128,BN=256 makes all grids multiples of 256 (768/512/256/256) AND the
//   3-buffer LDS (144KB) gives every DMA load >=2-5 phases to land with
//   vmcnt(6) derived waits (never 0 in loop).
//   - 512 thr = 8 waves (2M x 4N), each wave owns 64x64 out (acc[4][4]).
//   - Per K-tile: ph0 {DSB 8 + DSA 4 ds_read_b128; stage A(t+2)+B0(t+2);
//     bar; lgkm0; prio1; 16 MFMA; prio0; bar}, ph1 {DSA 4; stage B123(t+2);
//     bar; lgkm0; prio1; 16 MFMA; prio0; vmcnt(6); bar}.
//   - chunk ^= (row&7) XOR swizzle (pre-swizzled global src + swizzled
//     ds_read; measured SQ_LDS_BANK_CONFLICT == 0 with this involution).
//
// Workspace layout (136 MB, aliased by lifetime):
//   [0,16)MB    x_bf16        -> later VT (transpose runs after QKV gemm)
//   [16,22)MB   wq|wk|wv bf16 (contiguous -> fused [3072][1024] weight)
//   [22,24)MB   wo bf16
//   [24,72)MB   QKV bf16 [8192][3072] -> after QK^T: P=[24,56), O=[56,72)
//   [72,136)MB  S fp32 [4][2048][2048]; bqkv (12KB) lives at 72MB before S

typedef __bf16 bf16x8 __attribute__((ext_vector_type(8)));
typedef float f32x4 __attribute__((ext_vector_type(4)));

__device__ __forceinline__ unsigned short f32_to_bf16(float f) {
  unsigned int u = __float_as_uint(f);
  u += 0x7fffu + ((u >> 16) & 1u);   // round-to-nearest-even
  return (unsigned short)(u >> 16);
}

__device__ __forceinline__ void load_lds16(const void* g, void* l) {
  __builtin_amdgcn_global_load_lds(
      (const __attribute__((address_space(1))) void*)g,
      (__attribute__((address_space(3))) void*)l, 16, 0, 0);
}

// ---------------------------------------------------------------- cast kernel
__global__ __launch_bounds__(256) void cast_f32_bf16(
    const float4* __restrict__ in, ushort4* __restrict__ out, int n4) {
  int i = blockIdx.x * 256 + threadIdx.x;
  if (i < n4) {
    float4 f = in[i];
    ushort4 u;
    u.x = f32_to_bf16(f.x);
    u.y = f32_to_bf16(f.y);
    u.z = f32_to_bf16(f.z);
    u.w = f32_to_bf16(f.w);
    out[i] = u;
  }
}

// ------------------------------------------------------------ bias concat
__global__ __launch_bounds__(256) void concat3(
    const float* __restrict__ a, const float* __restrict__ b,
    const float* __restrict__ c, float* __restrict__ o) {
  int i = blockIdx.x * 256 + threadIdx.x;  // grid 12 -> i < 3072
  if (i < 1024)
    o[i] = a[i];
  else if (i < 2048)
    o[i] = b[i - 1024];
  else if (i < 3072)
    o[i] = c[i - 2048];
}

// ------------------------------------------- gemm (B^T form), 128x256 3-buf
// C[b][M][N] = alpha * A[b][M][K] * B[b][N][K]^T + bias[N]
// A row stride lda, B row stride ldb (for column-sliced QKV views).
// Requires M%128==0, N%256==0, K%64==0, K>=128.
__global__ __launch_bounds__(512, 2) void gemm_bt128x256(
    const unsigned short* __restrict__ A, const unsigned short* __restrict__ B,
    void* __restrict__ C, const float* __restrict__ bias,
    int M, int N, int K, float alpha, int out_bf16, int lda, int ldb,
    long long sA, long long sB, long long sC) {
  __shared__ unsigned short As[3][128][64];  // 48KB  [buf][row][k]
  __shared__ unsigned short Bs[3][256][64];  // 96KB

  const int bz = blockIdx.z;
  A += (long long)bz * sA;
  B += (long long)bz * sB;

  const int bm = blockIdx.y, bn = blockIdx.x;
  const int tid = threadIdx.x;
  const int lane = tid & 63, wave = tid >> 6;
  const int wr = wave >> 2;             // M 64-row slice (0..1)
  const int wc = wave & 3;              // N 64-col slice (0..3)
  const int l16 = lane & 15, quad = lane >> 4;
  // swizzled 16B-chunk element offsets for the two K-slices (row&7 == l16&7)
  const int pc0 = (quad ^ (l16 & 7)) * 8;
  const int pc1 = ((4 + quad) ^ (l16 & 7)) * 8;

  // staging map: thread t covers LDS row srow (+64j); physical chunk t&7 ->
  // fetch logical (swizzled) chunk lch from global. DMA dst is linear:
  // wave*1024 + lane*16 == row*128 + chunk*16 for row = srow, chunk = tid&7.
  const int srow = tid >> 3;
  const int lch = (tid & 7) ^ (srow & 7);
  const unsigned short* gA0 = A + (long long)(bm * 128 + srow) * lda + lch * 8;
  const unsigned short* gB0 = B + (long long)(bn * 256 + srow) * ldb + lch * 8;

  f32x4 acc[4][4] = {};
  bf16x8 af[2][2];  // 2 mi rows per phase
  bf16x8 bf[4][2];  // whole K-tile B fragments (loaded at ph0)

  const int NT = K >> 6;  // 64-wide K tiles

#define STG_A(BUF, KT)                                                      \
  do {                                                                      \
    const unsigned short* _s = gA0 + (long long)(KT) * 64;                  \
    char* _d = (char*)&As[BUF][0][0] + wave * 1024;                         \
    load_lds16(_s, _d);                                                     \
    load_lds16(_s + (long long)64 * lda, _d + 8192);                        \
  } while (0)
#define STG_B(BUF, KT, J0, JN)                                              \
  do {                                                                      \
    const unsigned short* _s = gB0 + (long long)(KT) * 64;                  \
    char* _d = (char*)&Bs[BUF][0][0] + wave * 1024;                         \
    _Pragma("unroll") for (int _j = (J0); _j < (JN); ++_j)                  \
        load_lds16(_s + (long long)(_j * 64) * ldb, _d + _j * 8192);        \
  } while (0)

#define DSA(BUF, P)                                                         \
  do {                                                                      \
    _Pragma("unroll") for (int m2 = 0; m2 < 2; ++m2) {                      \
      const unsigned short* _r =                                            \
          &As[BUF][wr * 64 + ((P) * 2 + m2) * 16 + l16][0];                 \
      af[m2][0] = *(const bf16x8*)(_r + pc0);                               \
      af[m2][1] = *(const bf16x8*)(_r + pc1);                               \
    }                                                                       \
  } while (0)

#define DSB(BUF)                                                            \
  do {                                                                      \
    _Pragma("unroll") for (int ni = 0; ni < 4; ++ni) {                      \
      const unsigned short* _r = &Bs[BUF][wc * 64 + ni * 16 + l16][0];      \
      bf[ni][0] = *(const bf16x8*)(_r + pc0);                               \
      bf[ni][1] = *(const bf16x8*)(_r + pc1);                               \
    }                                                                       \
  } while (0)

#define MM(P)                                                               \
  do {                                                                      \
    _Pragma("unroll") for (int m2 = 0; m2 < 2; ++m2)                        \
        _Pragma("unroll") for (int ni = 0; ni < 4; ++ni) {                  \
      f32x4* _a = &acc[(P) * 2 + m2][ni];                                   \
      *_a = __builtin_amdgcn_mfma_f32_16x16x32_bf16(af[m2][0], bf[ni][0],   \
                                                    *_a, 0, 0, 0);          \
      *_a = __builtin_amdgcn_mfma_f32_16x16x32_bf16(af[m2][1], bf[ni][1],   \
                                                    *_a, 0, 0, 0);          \
    }                                                                       \
  } while (0)

#define BAR() __builtin_amdgcn_s_barrier()
#define WLG() asm volatile("s_waitcnt lgkmcnt(0)" ::: "memory")
#define WVM6() asm volatile("s_waitcnt vmcnt(6)" ::: "memory")
#define P1() __builtin_amdgcn_s_setprio(1)
#define P0() __builtin_amdgcn_s_setprio(0)

  // prologue: tiles 0 -> buf0, 1 -> buf1 (6 loads/thread each).
  // vmcnt(6): tile 0 landed; tile 1's 6 loads may stay in flight.
  STG_A(0, 0);
  STG_B(0, 0, 0, 4);
  STG_A(1, 1);
  STG_B(1, 1, 0, 4);
  WVM6();
  BAR();

  // Steady state per tile t (buf cur): stage tile t+2 into buf (cur+2)%3 —
  // its previous occupant (tile t-1) was fully read before the last barrier.
  // vmcnt(6) at end of tile t retires tile t+1's 6 loads (issued during
  // t-1, >=2 phases earlier); tile t+2's 6 remain in flight.
  int cur = 0;
  for (int t = 0; t < NT; ++t) {
    int b2 = cur + 2;
    if (b2 >= 3) b2 -= 3;
    const int kt = (t + 2 < NT) ? t + 2 : NT - 1;  // clamped tail restage is
    // ph0                                         // harmless (unread buf)
    DSB(cur);
    DSA(cur, 0);
    STG_A(b2, kt);
    STG_B(b2, kt, 0, 1);
    BAR();
    WLG();
    P1();
    MM(0);
    P0();
    BAR();
    // ph1
    DSA(cur, 1);
    STG_B(b2, kt, 1, 4);
    BAR();
    WLG();
    P1();
    MM(1);
    P0();
    WVM6();
    BAR();
    ++cur;
    if (cur == 3) cur = 0;
  }
  // drain DMA before block exit
  asm volatile("s_waitcnt vmcnt(0)" ::: "memory");

  // epilogue: D row = quad*4+r, col = l16 within each 16x16 tile
  const long long orow0 = (long long)bm * 128 + wr * 64 + quad * 4;
  const int ocol0 = bn * 256 + wc * 64 + l16;
  if (out_bf16) {
    unsigned short* Cp = (unsigned short*)C + (long long)bz * sC;
#pragma unroll
    for (int mi = 0; mi < 4; ++mi)
#pragma unroll
      for (int ni = 0; ni < 4; ++ni) {
        const int col = ocol0 + ni * 16;
        const float bv = bias ? bias[col] : 0.f;
#pragma unroll
        for (int r = 0; r < 4; ++r) {
          const float o = acc[mi][ni][r] * alpha + bv;
          Cp[(orow0 + mi * 16 + r) * N + col] = f32_to_bf16(o);
        }
      }
  } else {
    float* Cp = (float*)C + (long long)bz * sC;
#pragma unroll
    for (int mi = 0; mi < 4; ++mi)
#pragma unroll
      for (int ni = 0; ni < 4; ++ni) {
        const int col = ocol0 + ni * 16;
        const float bv = bias ? bias[col] : 0.f;
#pragma unroll
        for (int r = 0; r < 4; ++r) {
          const float o = acc[mi][ni][r] * alpha + bv;
          Cp[(orow0 + mi * 16 + r) * N + col] = o;
        }
      }
  }
#undef STG_A
#undef STG_B
#undef DSA
#undef DSB
#undef MM
#undef BAR
#undef WLG
#undef WVM6
#undef P1
#undef P0
}

// ------------------------------------------------------- V transpose (bf16)
// V view: [4*2048][ldv] at column offset already folded into pointer.
// VT: [4][1024][2048]
__global__ __launch_bounds__(256) void transpose_v(
    const unsigned short* __restrict__ V, unsigned short* __restrict__ VT,
    int ldv) {
  __shared__ unsigned short tile[64][65];
  const int d0 = blockIdx.x * 64, s0 = blockIdx.y * 64, b = blockIdx.z;
  const int t = threadIdx.x;
  const unsigned short* src = V + ((long long)b * 2048 + s0) * ldv + d0;
#pragma unroll
  for (int i = 0; i < 16; i++) {
    int lin = t + i * 256;
    int r = lin >> 6, c = lin & 63;  // r: s-offset, c: d-offset
    tile[r][c] = src[(long long)r * ldv + c];
  }
  __syncthreads();
  unsigned short* dst = VT + ((long long)b * 1024 + d0) * 2048 + s0;
#pragma unroll
  for (int i = 0; i < 16; i++) {
    int lin = t + i * 256;
    int r = lin >> 6, c = lin & 63;  // r: d-offset, c: s-offset
    dst[(long long)r * 2048 + c] = tile[c][r];
  }
}

// ------------------------------------------------------------- row softmax
// S: [8192][2048] fp32 -> P: [8192][2048] bf16. One block per row.
__global__ __launch_bounds__(256) void softmax_rows(
    const float* __restrict__ S, unsigned short* __restrict__ P) {
  const long long row = blockIdx.x;
  const float* s = S + row * 2048;
  const int t = threadIdx.x;
  float v[8];
  float mx = -3.4e38f;
#pragma unroll
  for (int i = 0; i < 8; i++) {
    v[i] = s[t + i * 256];
    mx = fmaxf(mx, v[i]);
  }
#pragma unroll
  for (int o = 32; o >= 1; o >>= 1) mx = fmaxf(mx, __shfl_xor(mx, o));
  __shared__ float red[4], red2[4];
  if ((t & 63) == 0) red[t >> 6] = mx;
  __syncthreads();
  mx = fmaxf(fmaxf(red[0], red[1]), fmaxf(red[2], red[3]));
  float sum = 0.f;
#pragma unroll
  for (int i = 0; i < 8; i++) {
    v[i] = __expf(v[i] - mx);
    sum += v[i];
  }
#pragma unroll
  for (int o = 32; o >= 1; o >>= 1) sum += __shfl_xor(sum, o);
  if ((t & 63) == 0) red2[t >> 6] = sum;
  __syncthreads();
  sum = red2[0] + red2[1] + red2[2] + red2[3];
  const float inv = 1.0f / sum;
  unsigned short* p = P + row * 2048;
#pragma unroll
  for (int i = 0; i < 8; i++) p[t + i * 256] = f32_to_bf16(v[i] * inv);
}

// ----------------------------------------------------------------- launcher
extern "C" void kernel_launch(void* const* d_in, const int* in_sizes, int n_in,
                              void* d_out, int out_size, void* d_ws,
                              size_t ws_size, hipStream_t stream) {
  const float* x = (const float*)d_in[0];
  const float* wq = (const float*)d_in[1];
  const float* bq = (const float*)d_in[2];
  const float* wk = (const float*)d_in[3];
  const float* bk = (const float*)d_in[4];
  const float* wv = (const float*)d_in[5];
  const float* bv = (const float*)d_in[6];
  const float* wo = (const float*)d_in[7];
  const float* bo = (const float*)d_in[8];
  float* out = (float*)d_out;
  char* ws = (char*)d_ws;
  const size_t MB = 1ull << 20;

  unsigned short* xb   = (unsigned short*)(ws + 0);        // 16MB, later VT
  unsigned short* wqkv = (unsigned short*)(ws + 16 * MB);  // 6MB [3072][1024]
  unsigned short* wkb  = (unsigned short*)(ws + 18 * MB);
  unsigned short* wvb  = (unsigned short*)(ws + 20 * MB);
  unsigned short* wob  = (unsigned short*)(ws + 22 * MB);  // 2MB
  unsigned short* QKV  = (unsigned short*)(ws + 24 * MB);  // 48MB [8192][3072]
  float*          S    = (float*)(ws + 72 * MB);           // 64MB
  float*          bqkv = (float*)(ws + 72 * MB);           // 12KB, dies at S
  unsigned short* VT   = xb;                               // 16MB over x_bf16
  unsigned short* P    = QKV;                              // 32MB over QKV
  unsigned short* O    = (unsigned short*)(ws + 56 * MB);  // 16MB over QKV tail

  // 1) casts to bf16 (wq|wk|wv land contiguously -> fused weight)
  cast_f32_bf16<<<dim3(8192), dim3(256), 0, stream>>>((const float4*)x,
                                                      (ushort4*)xb, 2097152);
  cast_f32_bf16<<<dim3(1024), dim3(256), 0, stream>>>((const float4*)wq,
                                                      (ushort4*)wqkv, 262144);
  cast_f32_bf16<<<dim3(1024), dim3(256), 0, stream>>>((const float4*)wk,
                                                      (ushort4*)wkb, 262144);
  cast_f32_bf16<<<dim3(1024), dim3(256), 0, stream>>>((const float4*)wv,
                                                      (ushort4*)wvb, 262144);
  cast_f32_bf16<<<dim3(1024), dim3(256), 0, stream>>>((const float4*)wo,
                                                      (ushort4*)wob, 262144);
  concat3<<<dim3(12), dim3(256), 0, stream>>>(bq, bk, bv, bqkv);

  // 2) fused QKV projection: [8192,3072] = x_bf16 @ [wq;wk;wv]^T + bqkv
  //    grid 12x64 = 768 blocks = 3 full machine rounds
  gemm_bt128x256<<<dim3(12, 64, 1), dim3(512), 0, stream>>>(
      xb, wqkv, QKV, bqkv, 8192, 3072, 1024, 1.f, 1, 1024, 1024, 0, 0, 0);

  // 3) V (cols [2048,3072) of QKV) -> VT [4][1024][2048]
  transpose_v<<<dim3(16, 32, 4), dim3(256), 0, stream>>>(QKV + 2048, VT, 3072);

  // 4) S = Q K^T / 32, fp32, batched over 4 (Q,K are column slices of QKV)
  //    grid 8x16x4 = 512 blocks = 2 full rounds
  gemm_bt128x256<<<dim3(8, 16, 4), dim3(512), 0, stream>>>(
      QKV, QKV + 1024, S, nullptr, 2048, 2048, 1024, 0.03125f, 0, 3072, 3072,
      2048ll * 3072, 2048ll * 3072, 2048ll * 2048);

  // 5) P = softmax rows of S (bf16), over dead Q/K region
  softmax_rows<<<dim3(8192), dim3(256), 0, stream>>>(S, P);

  // 6) O = P @ V (via VT, B^T form), bf16 — grid 4x16x4 = 256 = 1 full round
  gemm_bt128x256<<<dim3(4, 16, 4), dim3(512), 0, stream>>>(
      P, VT, O, nullptr, 2048, 1024, 2048, 1.f, 1, 2048, 2048, 2048ll * 2048,
      1024ll * 2048, 2048ll * 1024);

  // 7) out = O @ Wo^T + bo, fp32 — grid 4x64 = 256 = 1 full round
  gemm_bt128x256<<<dim3(4, 64, 1), dim3(512), 0, stream>>>(
      O, wob, out, bo, 8192, 1024, 1024, 1.f, 0, 1024, 1024, 0, 0, 0);
}

// Round 4
// 314.262 us; speedup vs baseline: 1.2321x; 1.0010x over previous
//
#include <hip/hip_runtime.h>

// SelfAttention: x(4,2048,1024) fp32; Linear y = x @ W^T + b for Q,K,V;
// S = QK^T/32; P = softmax(S); O = P V; out = O @ Wo^T + bo.
// R6: deep-pipeline 256x256 engine (gemm_bt256dp) for QKV + QK^T.
//   R5 post-mortem: phases ran ~1880cy vs ~500cy model -> latency exposure
//   from 2-phase stage-to-read distance (m232 failure mode). Fix: stage each
//   half-tile 5-8 phases before first read (A 3-buf, B 2-buf, 160KB LDS),
//   vmcnt(8) once per K-step retires only loads >=4 phases old.
//   Per K-step t (A buf a=t%3, B buf b=t&1), 4 phases:
//     P1: ds_read B all (8 b128) + A mi01 (4); stage A0(t+2)->As[(t+2)%3]
//     P2: A mi23; stage A1(t+2)    P3: A mi45; stage B0(t+2)->Bs[b]
//     P4: A mi67; stage B1(t+2); vmcnt(8)
//   each phase: reads; stage; bar; lgkm0; prio1; 16 MFMA; prio0; bar.
//   B(t) regs (bf[4][2]) live P1-P4 so Bs[b] is stage-safe from P2.
// PV + out-proj keep R5's verified 128x256 3-buf engine (grids = 256 blocks).
//
// Workspace layout (136 MB, aliased by lifetime):
//   [0,16)MB    x_bf16        -> later VT (transpose runs after QKV gemm)
//   [16,22)MB   wq|wk|wv bf16 (contiguous -> fused [3072][1024] weight)
//   [22,24)MB   wo bf16
//   [24,72)MB   QKV bf16 [8192][3072] -> after QK^T: P=[24,56), O=[56,72)
//   [72,136)MB  S fp32 [4][2048][2048]; bqkv (12KB) lives at 72MB before S

typedef __bf16 bf16x8 __attribute__((ext_vector_type(8)));
typedef float f32x4 __attribute__((ext_vector_type(4)));

__device__ __forceinline__ unsigned short f32_to_bf16(float f) {
  unsigned int u = __float_as_uint(f);
  u += 0x7fffu + ((u >> 16) & 1u);   // round-to-nearest-even
  return (unsigned short)(u >> 16);
}

__device__ __forceinline__ void load_lds16(const void* g, void* l) {
  __builtin_amdgcn_global_load_lds(
      (const __attribute__((address_space(1))) void*)g,
      (__attribute__((address_space(3))) void*)l, 16, 0, 0);
}

// ---------------------------------------------------------------- cast kernel
__global__ __launch_bounds__(256) void cast_f32_bf16(
    const float4* __restrict__ in, ushort4* __restrict__ out, int n4) {
  int i = blockIdx.x * 256 + threadIdx.x;
  if (i < n4) {
    float4 f = in[i];
    ushort4 u;
    u.x = f32_to_bf16(f.x);
    u.y = f32_to_bf16(f.y);
    u.z = f32_to_bf16(f.z);
    u.w = f32_to_bf16(f.w);
    out[i] = u;
  }
}

// ------------------------------------------------------------ bias concat
__global__ __launch_bounds__(256) void concat3(
    const float* __restrict__ a, const float* __restrict__ b,
    const float* __restrict__ c, float* __restrict__ o) {
  int i = blockIdx.x * 256 + threadIdx.x;  // grid 12 -> i < 3072
  if (i < 1024)
    o[i] = a[i];
  else if (i < 2048)
    o[i] = b[i - 1024];
  else if (i < 3072)
    o[i] = c[i - 2048];
}

// --------------------------------- gemm (B^T form), 256^2 deep-pipeline
// C[b][M][N] = alpha * A[b][M][K] * B[b][N][K]^T + bias[N]
// Requires M%256==0, N%256==0, K%128==0, K>=128.
__global__ __launch_bounds__(512, 2) void gemm_bt256dp(
    const unsigned short* __restrict__ A, const unsigned short* __restrict__ B,
    void* __restrict__ C, const float* __restrict__ bias,
    int M, int N, int K, float alpha, int out_bf16, int lda, int ldb,
    long long sA, long long sB, long long sC) {
  __shared__ unsigned short As[3][2][128 * 64];  // 96KB [buf][half][row*64+k]
  __shared__ unsigned short Bs[2][2][128 * 64];  // 64KB  (total 160KB)

  const int bz = blockIdx.z;
  A += (long long)bz * sA;
  B += (long long)bz * sB;

  const int bm = blockIdx.y, bn = blockIdx.x;
  const int tid = threadIdx.x;
  const int lane = tid & 63, wave = tid >> 6;
  const int wr = wave >> 2;             // M half (128 rows)
  const int wc = wave & 3;              // N quarter (64 cols)
  const int l16 = lane & 15, quad = lane >> 4;
  const int wbh = wc >> 1;              // B half this wave reads
  const int wbr = (wc & 1) * 64 + l16;  // B row base within that half
  // swizzled 16B-chunk element offsets for the two K-slices (row&7 == l16&7)
  const int pc0 = (quad ^ (l16 & 7)) * 8;
  const int pc1 = ((4 + quad) ^ (l16 & 7)) * 8;

  // staging map: thread t covers rows srow, srow+64 of a 128-row half;
  // physical chunk t&7 -> fetch logical (swizzled) chunk lch from global.
  const int srow = tid >> 3;
  const int lch = (tid & 7) ^ (srow & 7);
  const unsigned short* gA0 = A + (long long)(bm * 256 + srow) * lda + lch * 8;
  const unsigned short* gB0 = B + (long long)(bn * 256 + srow) * ldb + lch * 8;

  f32x4 acc[8][4] = {};
  bf16x8 af[2][2];  // current mi-pair fragments
  bf16x8 bf[4][2];  // whole-K-step B fragments (read at P1, live P1-P4)

  const int NT = K >> 6;

#define STA(BUF, H, KT)                                                     \
  do {                                                                      \
    const unsigned short* _s =                                              \
        gA0 + (long long)(H) * 128 * lda + (long long)(KT) * 64;            \
    char* _d = (char*)&As[BUF][H][0] + wave * 1024;                         \
    load_lds16(_s, _d);                                                     \
    load_lds16(_s + (long long)64 * lda, _d + 8192);                        \
  } while (0)
#define STB(BUF, H, KT)                                                     \
  do {                                                                      \
    const unsigned short* _s =                                              \
        gB0 + (long long)(H) * 128 * ldb + (long long)(KT) * 64;            \
    char* _d = (char*)&Bs[BUF][H][0] + wave * 1024;                         \
    load_lds16(_s, _d);                                                     \
    load_lds16(_s + (long long)64 * ldb, _d + 8192);                        \
  } while (0)

#define DSAq(BUF, MIP)                                                      \
  do {                                                                      \
    _Pragma("unroll") for (int m2 = 0; m2 < 2; ++m2) {                      \
      const unsigned short* _r =                                            \
          &As[BUF][wr][(((MIP) * 2 + m2) * 16 + l16) * 64];                 \
      af[m2][0] = *(const bf16x8*)(_r + pc0);                               \
      af[m2][1] = *(const bf16x8*)(_r + pc1);                               \
    }                                                                       \
  } while (0)

#define DSBq(BUF)                                                           \
  do {                                                                      \
    _Pragma("unroll") for (int ni = 0; ni < 4; ++ni) {                      \
      const unsigned short* _r = &Bs[BUF][wbh][(wbr + ni * 16) * 64];       \
      bf[ni][0] = *(const bf16x8*)(_r + pc0);                               \
      bf[ni][1] = *(const bf16x8*)(_r + pc1);                               \
    }                                                                       \
  } while (0)

#define MMq(MIP)                                                            \
  do {                                                                      \
    _Pragma("unroll") for (int m2 = 0; m2 < 2; ++m2)                        \
        _Pragma("unroll") for (int ni = 0; ni < 4; ++ni) {                  \
      f32x4* _a = &acc[(MIP) * 2 + m2][ni];                                 \
      *_a = __builtin_amdgcn_mfma_f32_16x16x32_bf16(af[m2][0], bf[ni][0],   \
                                                    *_a, 0, 0, 0);          \
      *_a = __builtin_amdgcn_mfma_f32_16x16x32_bf16(af[m2][1], bf[ni][1],   \
                                                    *_a, 0, 0, 0);          \
    }                                                                       \
  } while (0)

#define BARx() __builtin_amdgcn_s_barrier()
#define WLGx() asm volatile("s_waitcnt lgkmcnt(0)" ::: "memory")
#define WVM8() asm volatile("s_waitcnt vmcnt(8)" ::: "memory")
#define PR1() __builtin_amdgcn_s_setprio(1)
#define PR0() __builtin_amdgcn_s_setprio(0)

  // prologue: A(t0),B(t0) then A(t1),B(t1) = 16 loads/thread.
  // vmcnt(8) retires t0's 8; t1's 8 stay in flight (retired by t0.P4's wait).
  STA(0, 0, 0);
  STA(0, 1, 0);
  STB(0, 0, 0);
  STB(0, 1, 0);
  STA(1, 0, 1);
  STA(1, 1, 1);
  STB(1, 0, 1);
  STB(1, 1, 1);
  WVM8();
  BARx();

  // Steady state: K-step t stages A(t+2) at P1-P2, B(t+2) at P3-P4.
  // Stage-to-first-read distance: A 7-8 phases, B 5-6 phases. vmcnt(8) at
  // P4 retires everything staged before this K-step => tile t+1 complete
  // (its halves were staged during t-1, 4-8 phases ago). Barrier after the
  // wait gives cross-wave DMA visibility.
  int a = 0;
  for (int t = 0; t < NT; ++t) {
    const int b = t & 1;
    int a2 = a + 2;
    if (a2 >= 3) a2 -= 3;
    const int kt2 = (t + 2 < NT) ? t + 2 : NT - 1;  // clamped tail restage
    // P1 (12 ds_reads)
    DSBq(b);
    DSAq(a, 0);
    STA(a2, 0, kt2);
    BARx();
    WLGx();
    PR1();
    MMq(0);
    PR0();
    BARx();
    // P2
    DSAq(a, 1);
    STA(a2, 1, kt2);
    BARx();
    WLGx();
    PR1();
    MMq(1);
    PR0();
    BARx();
    // P3 (Bs[b] stage-safe: B(t) regs read at P1)
    DSAq(a, 2);
    STB(b, 0, kt2);
    BARx();
    WLGx();
    PR1();
    MMq(2);
    PR0();
    BARx();
    // P4
    DSAq(a, 3);
    STB(b, 1, kt2);
    BARx();
    WLGx();
    PR1();
    MMq(3);
    PR0();
    WVM8();
    BARx();
    ++a;
    if (a == 3) a = 0;
  }
  asm volatile("s_waitcnt vmcnt(0)" ::: "memory");

  // epilogue: D row = quad*4+r, col = l16 within each 16x16 tile
  const long long orow0 = (long long)bm * 256 + wr * 128 + quad * 4;
  const int ocol0 = bn * 256 + wc * 64 + l16;
  if (out_bf16) {
    unsigned short* Cp = (unsigned short*)C + (long long)bz * sC;
#pragma unroll
    for (int mi = 0; mi < 8; ++mi)
#pragma unroll
      for (int ni = 0; ni < 4; ++ni) {
        const int col = ocol0 + ni * 16;
        const float bv = bias ? bias[col] : 0.f;
#pragma unroll
        for (int r = 0; r < 4; ++r) {
          const float o = acc[mi][ni][r] * alpha + bv;
          Cp[(orow0 + mi * 16 + r) * N + col] = f32_to_bf16(o);
        }
      }
  } else {
    float* Cp = (float*)C + (long long)bz * sC;
#pragma unroll
    for (int mi = 0; mi < 8; ++mi)
#pragma unroll
      for (int ni = 0; ni < 4; ++ni) {
        const int col = ocol0 + ni * 16;
        const float bv = bias ? bias[col] : 0.f;
#pragma unroll
        for (int r = 0; r < 4; ++r) {
          const float o = acc[mi][ni][r] * alpha + bv;
          Cp[(orow0 + mi * 16 + r) * N + col] = o;
        }
      }
  }
#undef STA
#undef STB
#undef DSAq
#undef DSBq
#undef MMq
#undef BARx
#undef WLGx
#undef WVM8
#undef PR1
#undef PR0
}

// ------------------------------------------- gemm (B^T form), 128x256 3-buf
// R5 engine, unchanged (verified): used for PV and out-proj (256-block grids).
__global__ __launch_bounds__(512, 2) void gemm_bt128x256(
    const unsigned short* __restrict__ A, const unsigned short* __restrict__ B,
    void* __restrict__ C, const float* __restrict__ bias,
    int M, int N, int K, float alpha, int out_bf16, int lda, int ldb,
    long long sA, long long sB, long long sC) {
  __shared__ unsigned short As[3][128][64];  // 48KB  [buf][row][k]
  __shared__ unsigned short Bs[3][256][64];  // 96KB

  const int bz = blockIdx.z;
  A += (long long)bz * sA;
  B += (long long)bz * sB;

  const int bm = blockIdx.y, bn = blockIdx.x;
  const int tid = threadIdx.x;
  const int lane = tid & 63, wave = tid >> 6;
  const int wr = wave >> 2;             // M 64-row slice (0..1)
  const int wc = wave & 3;              // N 64-col slice (0..3)
  const int l16 = lane & 15, quad = lane >> 4;
  const int pc0 = (quad ^ (l16 & 7)) * 8;
  const int pc1 = ((4 + quad) ^ (l16 & 7)) * 8;

  const int srow = tid >> 3;
  const int lch = (tid & 7) ^ (srow & 7);
  const unsigned short* gA0 = A + (long long)(bm * 128 + srow) * lda + lch * 8;
  const unsigned short* gB0 = B + (long long)(bn * 256 + srow) * ldb + lch * 8;

  f32x4 acc[4][4] = {};
  bf16x8 af[2][2];
  bf16x8 bf[4][2];

  const int NT = K >> 6;

#define STG_A(BUF, KT)                                                      \
  do {                                                                      \
    const unsigned short* _s = gA0 + (long long)(KT) * 64;                  \
    char* _d = (char*)&As[BUF][0][0] + wave * 1024;                         \
    load_lds16(_s, _d);                                                     \
    load_lds16(_s + (long long)64 * lda, _d + 8192);                        \
  } while (0)
#define STG_B(BUF, KT, J0, JN)                                              \
  do {                                                                      \
    const unsigned short* _s = gB0 + (long long)(KT) * 64;                  \
    char* _d = (char*)&Bs[BUF][0][0] + wave * 1024;                         \
    _Pragma("unroll") for (int _j = (J0); _j < (JN); ++_j)                  \
        load_lds16(_s + (long long)(_j * 64) * ldb, _d + _j * 8192);        \
  } while (0)

#define DSA(BUF, P)                                                         \
  do {                                                                      \
    _Pragma("unroll") for (int m2 = 0; m2 < 2; ++m2) {                      \
      const unsigned short* _r =                                            \
          &As[BUF][wr * 64 + ((P) * 2 + m2) * 16 + l16][0];                 \
      af[m2][0] = *(const bf16x8*)(_r + pc0);                               \
      af[m2][1] = *(const bf16x8*)(_r + pc1);                               \
    }                                                                       \
  } while (0)

#define DSB(BUF)                                                            \
  do {                                                                      \
    _Pragma("unroll") for (int ni = 0; ni < 4; ++ni) {                      \
      const unsigned short* _r = &Bs[BUF][wc * 64 + ni * 16 + l16][0];      \
      bf[ni][0] = *(const bf16x8*)(_r + pc0);                               \
      bf[ni][1] = *(const bf16x8*)(_r + pc1);                               \
    }                                                                       \
  } while (0)

#define MM(P)                                                               \
  do {                                                                      \
    _Pragma("unroll") for (int m2 = 0; m2 < 2; ++m2)                        \
        _Pragma("unroll") for (int ni = 0; ni < 4; ++ni) {                  \
      f32x4* _a = &acc[(P) * 2 + m2][ni];                                   \
      *_a = __builtin_amdgcn_mfma_f32_16x16x32_bf16(af[m2][0], bf[ni][0],   \
                                                    *_a, 0, 0, 0);          \
      *_a = __builtin_amdgcn_mfma_f32_16x16x32_bf16(af[m2][1], bf[ni][1],   \
                                                    *_a, 0, 0, 0);          \
    }                                                                       \
  } while (0)

#define BAR() __builtin_amdgcn_s_barrier()
#define WLG() asm volatile("s_waitcnt lgkmcnt(0)" ::: "memory")
#define WVM6() asm volatile("s_waitcnt vmcnt(6)" ::: "memory")
#define P1x() __builtin_amdgcn_s_setprio(1)
#define P0x() __builtin_amdgcn_s_setprio(0)

  STG_A(0, 0);
  STG_B(0, 0, 0, 4);
  STG_A(1, 1);
  STG_B(1, 1, 0, 4);
  WVM6();
  BAR();

  int cur = 0;
  for (int t = 0; t < NT; ++t) {
    int b2 = cur + 2;
    if (b2 >= 3) b2 -= 3;
    const int kt = (t + 2 < NT) ? t + 2 : NT - 1;
    // ph0
    DSB(cur);
    DSA(cur, 0);
    STG_A(b2, kt);
    STG_B(b2, kt, 0, 1);
    BAR();
    WLG();
    P1x();
    MM(0);
    P0x();
    BAR();
    // ph1
    DSA(cur, 1);
    STG_B(b2, kt, 1, 4);
    BAR();
    WLG();
    P1x();
    MM(1);
    P0x();
    WVM6();
    BAR();
    ++cur;
    if (cur == 3) cur = 0;
  }
  asm volatile("s_waitcnt vmcnt(0)" ::: "memory");

  const long long orow0 = (long long)bm * 128 + wr * 64 + quad * 4;
  const int ocol0 = bn * 256 + wc * 64 + l16;
  if (out_bf16) {
    unsigned short* Cp = (unsigned short*)C + (long long)bz * sC;
#pragma unroll
    for (int mi = 0; mi < 4; ++mi)
#pragma unroll
      for (int ni = 0; ni < 4; ++ni) {
        const int col = ocol0 + ni * 16;
        const float bv = bias ? bias[col] : 0.f;
#pragma unroll
        for (int r = 0; r < 4; ++r) {
          const float o = acc[mi][ni][r] * alpha + bv;
          Cp[(orow0 + mi * 16 + r) * N + col] = f32_to_bf16(o);
        }
      }
  } else {
    float* Cp = (float*)C + (long long)bz * sC;
#pragma unroll
    for (int mi = 0; mi < 4; ++mi)
#pragma unroll
      for (int ni = 0; ni < 4; ++ni) {
        const int col = ocol0 + ni * 16;
        const float bv = bias ? bias[col] : 0.f;
#pragma unroll
        for (int r = 0; r < 4; ++r) {
          const float o = acc[mi][ni][r] * alpha + bv;
          Cp[(orow0 + mi * 16 + r) * N + col] = o;
        }
      }
  }
#undef STG_A
#undef STG_B
#undef DSA
#undef DSB
#undef MM
#undef BAR
#undef WLG
#undef WVM6
#undef P1x
#undef P0x
}

// ------------------------------------------------------- V transpose (bf16)
__global__ __launch_bounds__(256) void transpose_v(
    const unsigned short* __restrict__ V, unsigned short* __restrict__ VT,
    int ldv) {
  __shared__ unsigned short tile[64][65];
  const int d0 = blockIdx.x * 64, s0 = blockIdx.y * 64, b = blockIdx.z;
  const int t = threadIdx.x;
  const unsigned short* src = V + ((long long)b * 2048 + s0) * ldv + d0;
#pragma unroll
  for (int i = 0; i < 16; i++) {
    int lin = t + i * 256;
    int r = lin >> 6, c = lin & 63;
    tile[r][c] = src[(long long)r * ldv + c];
  }
  __syncthreads();
  unsigned short* dst = VT + ((long long)b * 1024 + d0) * 2048 + s0;
#pragma unroll
  for (int i = 0; i < 16; i++) {
    int lin = t + i * 256;
    int r = lin >> 6, c = lin & 63;
    dst[(long long)r * 2048 + c] = tile[c][r];
  }
}

// ------------------------------------------------------------- row softmax
__global__ __launch_bounds__(256) void softmax_rows(
    const float* __restrict__ S, unsigned short* __restrict__ P) {
  const long long row = blockIdx.x;
  const float* s = S + row * 2048;
  const int t = threadIdx.x;
  float v[8];
  float mx = -3.4e38f;
#pragma unroll
  for (int i = 0; i < 8; i++) {
    v[i] = s[t + i * 256];
    mx = fmaxf(mx, v[i]);
  }
#pragma unroll
  for (int o = 32; o >= 1; o >>= 1) mx = fmaxf(mx, __shfl_xor(mx, o));
  __shared__ float red[4], red2[4];
  if ((t & 63) == 0) red[t >> 6] = mx;
  __syncthreads();
  mx = fmaxf(fmaxf(red[0], red[1]), fmaxf(red[2], red[3]));
  float sum = 0.f;
#pragma unroll
  for (int i = 0; i < 8; i++) {
    v[i] = __expf(v[i] - mx);
    sum += v[i];
  }
#pragma unroll
  for (int o = 32; o >= 1; o >>= 1) sum += __shfl_xor(sum, o);
  if ((t & 63) == 0) red2[t >> 6] = sum;
  __syncthreads();
  sum = red2[0] + red2[1] + red2[2] + red2[3];
  const float inv = 1.0f / sum;
  unsigned short* p = P + row * 2048;
#pragma unroll
  for (int i = 0; i < 8; i++) p[t + i * 256] = f32_to_bf16(v[i] * inv);
}

// ----------------------------------------------------------------- launcher
extern "C" void kernel_launch(void* const* d_in, const int* in_sizes, int n_in,
                              void* d_out, int out_size, void* d_ws,
                              size_t ws_size, hipStream_t stream) {
  const float* x = (const float*)d_in[0];
  const float* wq = (const float*)d_in[1];
  const float* bq = (const float*)d_in[2];
  const float* wk = (const float*)d_in[3];
  const float* bk = (const float*)d_in[4];
  const float* wv = (const float*)d_in[5];
  const float* bv = (const float*)d_in[6];
  const float* wo = (const float*)d_in[7];
  const float* bo = (const float*)d_in[8];
  float* out = (float*)d_out;
  char* ws = (char*)d_ws;
  const size_t MB = 1ull << 20;

  unsigned short* xb   = (unsigned short*)(ws + 0);        // 16MB, later VT
  unsigned short* wqkv = (unsigned short*)(ws + 16 * MB);  // 6MB [3072][1024]
  unsigned short* wkb  = (unsigned short*)(ws + 18 * MB);
  unsigned short* wvb  = (unsigned short*)(ws + 20 * MB);
  unsigned short* wob  = (unsigned short*)(ws + 22 * MB);  // 2MB
  unsigned short* QKV  = (unsigned short*)(ws + 24 * MB);  // 48MB [8192][3072]
  float*          S    = (float*)(ws + 72 * MB);           // 64MB
  float*          bqkv = (float*)(ws + 72 * MB);           // 12KB, dies at S
  unsigned short* VT   = xb;                               // 16MB over x_bf16
  unsigned short* P    = QKV;                              // 32MB over QKV
  unsigned short* O    = (unsigned short*)(ws + 56 * MB);  // 16MB over QKV tail

  // 1) casts to bf16 (wq|wk|wv land contiguously -> fused weight)
  cast_f32_bf16<<<dim3(8192), dim3(256), 0, stream>>>((const float4*)x,
                                                      (ushort4*)xb, 2097152);
  cast_f32_bf16<<<dim3(1024), dim3(256), 0, stream>>>((const float4*)wq,
                                                      (ushort4*)wqkv, 262144);
  cast_f32_bf16<<<dim3(1024), dim3(256), 0, stream>>>((const float4*)wk,
                                                      (ushort4*)wkb, 262144);
  cast_f32_bf16<<<dim3(1024), dim3(256), 0, stream>>>((const float4*)wv,
                                                      (ushort4*)wvb, 262144);
  cast_f32_bf16<<<dim3(1024), dim3(256), 0, stream>>>((const float4*)wo,
                                                      (ushort4*)wob, 262144);
  concat3<<<dim3(12), dim3(256), 0, stream>>>(bq, bk, bv, bqkv);

  // 2) fused QKV projection: [8192,3072] = x_bf16 @ [wq;wk;wv]^T + bqkv
  //    deep-pipeline 256^2 engine, grid 12x32 = 384 blocks (1.5 rounds)
  gemm_bt256dp<<<dim3(12, 32, 1), dim3(512), 0, stream>>>(
      xb, wqkv, QKV, bqkv, 8192, 3072, 1024, 1.f, 1, 1024, 1024, 0, 0, 0);

  // 3) V (cols [2048,3072) of QKV) -> VT [4][1024][2048]
  transpose_v<<<dim3(16, 32, 4), dim3(256), 0, stream>>>(QKV + 2048, VT, 3072);

  // 4) S = Q K^T / 32, fp32, batched over 4 (Q,K are column slices of QKV)
  //    deep-pipeline 256^2 engine, grid 8x8x4 = 256 blocks (1 full round)
  gemm_bt256dp<<<dim3(8, 8, 4), dim3(512), 0, stream>>>(
      QKV, QKV + 1024, S, nullptr, 2048, 2048, 1024, 0.03125f, 0, 3072, 3072,
      2048ll * 3072, 2048ll * 3072, 2048ll * 2048);

  // 5) P = softmax rows of S (bf16), over dead Q/K region
  softmax_rows<<<dim3(8192), dim3(256), 0, stream>>>(S, P);

  // 6) O = P @ V (via VT, B^T form), bf16 — grid 4x16x4 = 256 = 1 full round
  gemm_bt128x256<<<dim3(4, 16, 4), dim3(512), 0, stream>>>(
      P, VT, O, nullptr, 2048, 1024, 2048, 1.f, 1, 2048, 2048, 2048ll * 2048,
      1024ll * 2048, 2048ll * 1024);

  // 7) out = O @ Wo^T + bo, fp32 — grid 4x64 = 256 = 1 full round
  gemm_bt128x256<<<dim3(4, 64, 1), dim3(512), 0, stream>>>(
      O, wob, out, bo, 8192, 1024, 1024, 1.f, 0, 1024, 1024, 0, 0, 0);
}